// Round 9
// baseline (233.794 us; speedup 1.0000x reference)
//
#include <hip/hip_runtime.h>
#include <hip/hip_bf16.h>

// Fused LN -> QKV projection (bf16 MFMA, 256^2, balanced 4-phase k-slice
// schedule, 2D-clustered XCD mapping) with RoPE fused into the GEMM epilogue.
// x:(2,4096,2048) f32; wq/wk/wv:(2048,2048) f32 row-major [e][d]; out: q,k,v
// each (2,16,4096,128) f32 concatenated.

typedef float f32x4 __attribute__((ext_vector_type(4)));
typedef __bf16 bf16x8 __attribute__((ext_vector_type(8)));
typedef __bf16 bf16x4 __attribute__((ext_vector_type(4)));

#define DM    2048
#define NSEQ  4096
#define NH    16
#define HD    128
#define NROWS 8192
#define MAT_ELEMS (2ull*NH*NSEQ*HD)

// ---------- async global->LDS (16B/lane, wave-uniform LDS base) --------------
typedef __attribute__((address_space(1))) const void GV;
typedef __attribute__((address_space(3))) void LV;
__device__ __forceinline__ void gload_lds16(const void* g, void* l) {
    __builtin_amdgcn_global_load_lds((GV*)g, (LV*)l, 16, 0, 0);
}

// ---------------------- LayerNorm + bf16 cast --------------------------------
__global__ __launch_bounds__(256)
void ln_kernel(const float* __restrict__ x, const float* __restrict__ g,
               const float* __restrict__ be, __bf16* __restrict__ xnb) {
    int row = blockIdx.x;
    int tid = threadIdx.x;
    const float4* xr = (const float4*)(x + (size_t)row * DM);
    float4 v0 = xr[tid];
    float4 v1 = xr[tid + 256];
    float s  = v0.x + v0.y + v0.z + v0.w + v1.x + v1.y + v1.z + v1.w;
    float ss = v0.x*v0.x + v0.y*v0.y + v0.z*v0.z + v0.w*v0.w
             + v1.x*v1.x + v1.y*v1.y + v1.z*v1.z + v1.w*v1.w;
#pragma unroll
    for (int o = 32; o > 0; o >>= 1) {
        s  += __shfl_down(s, o);
        ss += __shfl_down(ss, o);
    }
    __shared__ float red[10];
    int wave = tid >> 6, lane = tid & 63;
    if (lane == 0) { red[wave] = s; red[4 + wave] = ss; }
    __syncthreads();
    if (tid == 0) {
        float S  = red[0] + red[1] + red[2] + red[3];
        float SS = red[4] + red[5] + red[6] + red[7];
        float mu  = S * (1.0f / DM);
        float var = SS * (1.0f / DM) - mu * mu;
        red[8] = mu;
        red[9] = rsqrtf(var + 1e-5f);
    }
    __syncthreads();
    float mu = red[8], rs = red[9];

    const float4* gp = (const float4*)g;
    const float4* bp = (const float4*)be;
    bf16x4* orow = (bf16x4*)(xnb + (size_t)row * DM);
    {
        float4 g0 = gp[tid], b0 = bp[tid];
        bf16x4 o;
        o[0] = (__bf16)((v0.x - mu) * rs * g0.x + b0.x);
        o[1] = (__bf16)((v0.y - mu) * rs * g0.y + b0.y);
        o[2] = (__bf16)((v0.z - mu) * rs * g0.z + b0.z);
        o[3] = (__bf16)((v0.w - mu) * rs * g0.w + b0.w);
        orow[tid] = o;
    }
    {
        float4 g1 = gp[tid + 256], b1 = bp[tid + 256];
        bf16x4 o;
        o[0] = (__bf16)((v1.x - mu) * rs * g1.x + b1.x);
        o[1] = (__bf16)((v1.y - mu) * rs * g1.y + b1.y);
        o[2] = (__bf16)((v1.z - mu) * rs * g1.z + b1.z);
        o[3] = (__bf16)((v1.w - mu) * rs * g1.w + b1.w);
        orow[tid + 256] = o;
    }
}

// ---------------- f32 -> bf16 conversion, all 3 weights in one launch --------
__global__ __launch_bounds__(256)
void cvt3_kernel(const float* __restrict__ a0, const float* __restrict__ a1,
                 const float* __restrict__ a2, __bf16* __restrict__ o) {
    int bid = blockIdx.x;                       // 0..6143
    const float* a = (bid < 2048) ? a0 : (bid < 4096) ? a1 : a2;
    size_t base = ((size_t)(bid & 2047) * 256 + threadIdx.x) * 8;
    float4 v0 = *(const float4*)(a + base);
    float4 v1 = *(const float4*)(a + base + 4);
    bf16x8 r;
    r[0] = (__bf16)v0.x; r[1] = (__bf16)v0.y; r[2] = (__bf16)v0.z; r[3] = (__bf16)v0.w;
    r[4] = (__bf16)v1.x; r[5] = (__bf16)v1.y; r[6] = (__bf16)v1.z; r[7] = (__bf16)v1.w;
    *(bf16x8*)(o + (size_t)(bid >> 11) * 4194304 + base) = r;
}

// =====================  256x256 balanced 4-phase QKV GEMM  ===================
// Tile 256x256, BK=64, 8 waves (2Mx4N), LDS 128KiB dbuf, XOR-swizzle.
// Units: U0=A rows{0-63,128-191}, U1=A rows{64-127,192-255}; U2/U3 same for B.
// Reads: ph0/ph1 read U0,U2,U3(kt) (ks0/ks1 cols); ph2/ph3 read U1(kt).
// Stages: ph0 -> U1(kt+1) into Q; ph2 -> U0,U2(kt+2) into P; ph3 -> U3(kt+2).
//
// Load numbering (8/K-tile; prologue 14).  Wait derivation:
//   W0 (ph0, after stage) covers U1(kt) [staged kt-1 ph0]; newer = kt-1 ph2(4)
//     + kt-1 ph3(2) + kt ph0(2) = 8  -> vmcnt(8).
//   W2 (ph2, after stage) covers U0,U2,U3(kt+1) [newest: U3 staged kt-1 ph3];
//     newer = kt ph0(2) + kt ph2(4) = 6 -> vmcnt(6).
//   Pre-loop: 14 issued, need 1-6 (U0,U2,U3(0)) -> vmcnt(8) + BAR.
//   Tail: kt30 (no ph2/ph3 stage): W0=8, W2 covers U3(31) newer = kt30 ph0(2)
//     -> vmcnt(2).  kt31 (no stage): W0 covers U1(31) newer=0 -> vmcnt(0).

__device__ __forceinline__ void loadA(bf16x8 (&a)[4], const __bf16* Sp,
                                      int base, int oo) {
#pragma unroll
    for (int mi = 0; mi < 4; mi++)
        a[mi] = *(const bf16x8*)(Sp + base + mi * 1024 + oo);
}
__device__ __forceinline__ void loadB(bf16x8 (&b)[4], const __bf16* Sp,
                                      int base, int oo) {
#pragma unroll
    for (int j = 0; j < 4; j++)
        b[j] = *(const bf16x8*)(Sp + base + (j * 16 + (j >> 1) * 32) * 64 + oo);
}

template<int RB>
__device__ __forceinline__ void cluster(f32x4 (&acc)[8][4], bf16x8 (&a)[4],
                                        bf16x8 (&b)[4]) {
    __builtin_amdgcn_s_setprio(1);
#pragma unroll
    for (int mi = 0; mi < 4; mi++)
#pragma unroll
        for (int ni = 0; ni < 4; ni++)
            acc[RB + mi][ni] = __builtin_amdgcn_mfma_f32_16x16x32_bf16(
                a[mi], b[ni], acc[RB + mi][ni], 0, 0, 0);
    __builtin_amdgcn_s_setprio(0);
}

#define FENCE asm volatile("" ::: "memory")
#define BAR   do { FENCE; __builtin_amdgcn_s_barrier(); FENCE; } while (0)
#define VM8   asm volatile("s_waitcnt vmcnt(8)" ::: "memory")
#define VM6   asm volatile("s_waitcnt vmcnt(6)" ::: "memory")
#define VM2   asm volatile("s_waitcnt vmcnt(2)" ::: "memory")
#define VM0   asm volatile("s_waitcnt vmcnt(0)" ::: "memory")
#define VMX   do {} while (0)

// stage A/B half HF (0: rows {0-63,128-191}; 1: rows {64-127,192-255}) of
// K-tile kt into buf P.  Per-wave: rowgroups {HF*8+w, HF*8+16+w}.
#define STGA(P, kt, HF) do { \
    gload_lds16(pA + (size_t)((HF) * 64 + w * 8) * DM + (kt) * 64,       &As[P][((HF) * 8 + w) * 512]); \
    gload_lds16(pA + (size_t)((HF) * 64 + 128 + w * 8) * DM + (kt) * 64, &As[P][((HF) * 8 + 16 + w) * 512]); \
} while (0)
#define STGB(P, kt, HF) do { \
    gload_lds16(pB + (size_t)((HF) * 64 + w * 8) * DM + (kt) * 64,       &Bs[P][((HF) * 8 + w) * 512]); \
    gload_lds16(pB + (size_t)((HF) * 64 + 128 + w * 8) * DM + (kt) * 64, &Bs[P][((HF) * 8 + 16 + w) * 512]); \
} while (0)

#define KTILE(kt, P, Q, SG0, SG2, SG3, W0, W2) do { \
    /* ph0: m0-3 x ks0 */ \
    loadA(a0, &As[P][0], baseA, o0); \
    loadB(b0, &Bs[P][0], baseB, o0); \
    if (SG0) STGA(Q, (kt) + 1, 1); \
    W0; BAR; cluster<0>(acc, a0, b0); BAR; \
    /* ph1: m0-3 x ks1 */ \
    loadA(a1, &As[P][0], baseA, o1); \
    loadB(b1, &Bs[P][0], baseB, o1); \
    BAR; cluster<0>(acc, a1, b1); BAR; \
    /* ph2: m4-7 x ks0 (b0 reused) */ \
    loadA(a0, &As[P][0], baseA + 4096, o0); \
    if (SG2) { STGA(P, (kt) + 2, 0); STGB(P, (kt) + 2, 0); } \
    W2; BAR; cluster<4>(acc, a0, b0); BAR; \
    /* ph3: m4-7 x ks1 (b1 reused) */ \
    loadA(a1, &As[P][0], baseA + 4096, o1); \
    if (SG3) STGB(P, (kt) + 2, 1); \
    BAR; cluster<4>(acc, a1, b1); BAR; \
} while (0)

__global__ __launch_bounds__(512, 2)
void gemm_qkv(const __bf16* __restrict__ A,
              const __bf16* __restrict__ Wq,
              const __bf16* __restrict__ Wk,
              const __bf16* __restrict__ Wv,
              float* __restrict__ out) {
    __shared__ __bf16 As[2][16384];   // 2 x 256x64
    __shared__ __bf16 Bs[2][16384];

    int tid = threadIdx.x;
    int w = tid >> 6, l = tid & 63;
    int wm = w >> 2, wn = w & 3;

    // 2D-clustered XCD mapping (R6, verified): xcd owns 8mt x 12nt region;
    // each round's 32 co-resident blocks form a 4x8 / 8x4 cluster in L2.
    int bid = blockIdx.x;
    int x = bid & 7;
    int ridx = bid >> 3;               // 0..95
    int q = ridx >> 5;                 // round 0,1,2
    int s = ridx & 31;
    int mtp, ntp;
    if (q == 0)      { mtp = s >> 3;       ntp = s & 7; }
    else if (q == 1) { mtp = 4 + (s >> 3); ntp = s & 7; }
    else             { mtp = s & 7;        ntp = 8 + (s >> 3); }
    int mt = (x & 3) * 8 + mtp;        // 0..31
    int nt = (x >> 2) * 12 + ntp;      // 0..23
    int mat = nt >> 3, ntb = nt & 7;
    const __bf16* Wp = (mat == 0) ? Wq : (mat == 1) ? Wk : Wv;
    int row0 = mt * 256, colp = ntb * 256;

    // staging base pointers: lane covers row lr of each 8-row group, 16B at
    // pre-swizzled col ((l&7)^(l>>3))*16B  (rule 21: swizzle source, linear dest)
    int lr = l >> 3;
    int lco = ((l & 7) ^ lr) * 8;
    const __bf16* pA = A  + (size_t)(row0 + lr) * DM + lco;
    const __bf16* pB = Wp + (size_t)(colp + lr) * DM + lco;

    // ds_read lane constants (elements); read-side XOR matches write swizzle
    int baseA = (wm * 128 + (l & 15)) * 64;
    int baseB = ((wn & 1) * 32 + (wn >> 1) * 128 + (l & 15)) * 64;
    int o0 = ((l >> 4) * 8) ^ ((l & 7) * 8);
    int o1 = o0 ^ 32;

    // prologue: U0,U2,U3,U1(kt0)->buf0 ; U0,U2,U3(kt1)->buf1  (14 loads)
    STGA(0, 0, 0); STGB(0, 0, 0); STGB(0, 0, 1); STGA(0, 0, 1);
    STGA(1, 1, 0); STGB(1, 1, 0); STGB(1, 1, 1);

    f32x4 acc[8][4];
#pragma unroll
    for (int i = 0; i < 8; i++)
#pragma unroll
        for (int j = 0; j < 4; j++)
            acc[i][j] = (f32x4){0.f, 0.f, 0.f, 0.f};

    bf16x8 a0[4], a1[4], b0[4], b1[4];

    VM8;          // loads 1-6 = U0,U2,U3(kt0) landed before first ds_read
    BAR;

#pragma unroll 1
    for (int kt = 0; kt < 30; kt += 2) {
        KTILE(kt,     0, 1, 1, 1, 1, VM8, VM6);
        KTILE(kt + 1, 1, 0, 1, 1, 1, VM8, VM6);
    }
    KTILE(30, 0, 1, 1, 0, 0, VM8, VM2);   // stages only U1(31)
    KTILE(31, 1, 0, 0, 0, 0, VM0, VMX);

    // ---------------- epilogue: head-split layout + fused RoPE ---------------
    // acc[mi][ni] col = (wn&1)*32 + (ni&1)*16 + (wn>>1)*128 + (ni>>1)*64 + (l&15)
    // -> (acc[mi][ni], acc[mi][ni+2]) is the (d, d+64) rotation pair, ni=0,1.
    float* op = out + (size_t)mat * MAT_ELEMS;
    int hd_lo = (wn & 1) * 32 + (l & 15);                 // d for ni=0 (0..63)
    int head = ntb * 2 + (wn >> 1);
    int r_base = row0 + wm * 128 + ((l >> 4) << 2);
    float if0 = exp2f(-0.20762051f * (float)hd_lo);        // 10000^(-d/64)
    float if1 = exp2f(-0.20762051f * (float)(hd_lo + 16));

    if (mat < 2) {
#pragma unroll
        for (int mi = 0; mi < 8; mi++) {
#pragma unroll
            for (int j = 0; j < 4; j++) {
                int r = r_base + mi * 16 + j;
                int b = r >> 12, n = r & 4095;
                float fn = (float)n;
                float* rowp = op + ((size_t)((b * NH + head) * NSEQ + n)) * HD;
#pragma unroll
                for (int ni = 0; ni < 2; ni++) {
                    float lo = acc[mi][ni][j], hi = acc[mi][ni + 2][j];
                    float sv, cv;
                    __sincosf(fn * (ni ? if1 : if0), &sv, &cv);
                    rowp[hd_lo + ni * 16]      = lo * cv - hi * sv;
                    rowp[hd_lo + ni * 16 + 64] = hi * cv + lo * sv;
                }
            }
        }
    } else {
#pragma unroll
        for (int mi = 0; mi < 8; mi++) {
#pragma unroll
            for (int j = 0; j < 4; j++) {
                int r = r_base + mi * 16 + j;
                int b = r >> 12, n = r & 4095;
                float* rowp = op + ((size_t)((b * NH + head) * NSEQ + n)) * HD;
#pragma unroll
                for (int ni = 0; ni < 2; ni++) {
                    rowp[hd_lo + ni * 16]      = acc[mi][ni][j];
                    rowp[hd_lo + ni * 16 + 64] = acc[mi][ni + 2][j];
                }
            }
        }
    }
}

// ---------------------------------------------------------------------------
extern "C" void kernel_launch(void* const* d_in, const int* in_sizes, int n_in,
                              void* d_out, int out_size, void* d_ws, size_t ws_size,
                              hipStream_t stream) {
    const float* x  = (const float*)d_in[0];
    const float* g  = (const float*)d_in[1];
    const float* be = (const float*)d_in[2];
    const float* wq = (const float*)d_in[3];
    const float* wk = (const float*)d_in[4];
    const float* wv = (const float*)d_in[5];
    float* out = (float*)d_out;

    char* ws = (char*)d_ws;
    __bf16* xnb = (__bf16*)ws;                                   // 32 MB
    __bf16* wb  = (__bf16*)(ws + 33554432);                      // 24 MB (q,k,v)

    ln_kernel<<<NROWS, 256, 0, stream>>>(x, g, be, xnb);
    cvt3_kernel<<<6144, 256, 0, stream>>>(wq, wk, wv, wb);
    gemm_qkv<<<768, 512, 0, stream>>>(xnb, wb, wb + 4194304, wb + 8388608, out);
}

// Round 10
// 231.279 us; speedup vs baseline: 1.0109x; 1.0109x over previous
//
#include <hip/hip_runtime.h>
#include <hip/hip_bf16.h>

// Fused LN -> QKV projection (bf16 MFMA, 256^2, 2-phase/K-tile schedule,
// 2D-clustered XCD mapping) with RoPE fused into the GEMM epilogue.
// x:(2,4096,2048) f32; wq/wk/wv:(2048,2048) f32 row-major [e][d]; out: q,k,v
// each (2,16,4096,128) f32 concatenated.

typedef float f32x4 __attribute__((ext_vector_type(4)));
typedef __bf16 bf16x8 __attribute__((ext_vector_type(8)));
typedef __bf16 bf16x4 __attribute__((ext_vector_type(4)));

#define DM    2048
#define NSEQ  4096
#define NH    16
#define HD    128
#define NROWS 8192
#define MAT_ELEMS (2ull*NH*NSEQ*HD)

// ---------- async global->LDS (16B/lane, wave-uniform LDS base) --------------
typedef __attribute__((address_space(1))) const void GV;
typedef __attribute__((address_space(3))) void LV;
__device__ __forceinline__ void gload_lds16(const void* g, void* l) {
    __builtin_amdgcn_global_load_lds((GV*)g, (LV*)l, 16, 0, 0);
}

// ---------------------- LayerNorm + bf16 cast --------------------------------
__global__ __launch_bounds__(256)
void ln_kernel(const float* __restrict__ x, const float* __restrict__ g,
               const float* __restrict__ be, __bf16* __restrict__ xnb) {
    int row = blockIdx.x;
    int tid = threadIdx.x;
    const float4* xr = (const float4*)(x + (size_t)row * DM);
    float4 v0 = xr[tid];
    float4 v1 = xr[tid + 256];
    float s  = v0.x + v0.y + v0.z + v0.w + v1.x + v1.y + v1.z + v1.w;
    float ss = v0.x*v0.x + v0.y*v0.y + v0.z*v0.z + v0.w*v0.w
             + v1.x*v1.x + v1.y*v1.y + v1.z*v1.z + v1.w*v1.w;
#pragma unroll
    for (int o = 32; o > 0; o >>= 1) {
        s  += __shfl_down(s, o);
        ss += __shfl_down(ss, o);
    }
    __shared__ float red[10];
    int wave = tid >> 6, lane = tid & 63;
    if (lane == 0) { red[wave] = s; red[4 + wave] = ss; }
    __syncthreads();
    if (tid == 0) {
        float S  = red[0] + red[1] + red[2] + red[3];
        float SS = red[4] + red[5] + red[6] + red[7];
        float mu  = S * (1.0f / DM);
        float var = SS * (1.0f / DM) - mu * mu;
        red[8] = mu;
        red[9] = rsqrtf(var + 1e-5f);
    }
    __syncthreads();
    float mu = red[8], rs = red[9];

    const float4* gp = (const float4*)g;
    const float4* bp = (const float4*)be;
    bf16x4* orow = (bf16x4*)(xnb + (size_t)row * DM);
    {
        float4 g0 = gp[tid], b0 = bp[tid];
        bf16x4 o;
        o[0] = (__bf16)((v0.x - mu) * rs * g0.x + b0.x);
        o[1] = (__bf16)((v0.y - mu) * rs * g0.y + b0.y);
        o[2] = (__bf16)((v0.z - mu) * rs * g0.z + b0.z);
        o[3] = (__bf16)((v0.w - mu) * rs * g0.w + b0.w);
        orow[tid] = o;
    }
    {
        float4 g1 = gp[tid + 256], b1 = bp[tid + 256];
        bf16x4 o;
        o[0] = (__bf16)((v1.x - mu) * rs * g1.x + b1.x);
        o[1] = (__bf16)((v1.y - mu) * rs * g1.y + b1.y);
        o[2] = (__bf16)((v1.z - mu) * rs * g1.z + b1.z);
        o[3] = (__bf16)((v1.w - mu) * rs * g1.w + b1.w);
        orow[tid + 256] = o;
    }
}

// ---------------- f32 -> bf16 conversion, all 3 weights in one launch --------
__global__ __launch_bounds__(256)
void cvt3_kernel(const float* __restrict__ a0, const float* __restrict__ a1,
                 const float* __restrict__ a2, __bf16* __restrict__ o) {
    int bid = blockIdx.x;                       // 0..6143
    const float* a = (bid < 2048) ? a0 : (bid < 4096) ? a1 : a2;
    size_t base = ((size_t)(bid & 2047) * 256 + threadIdx.x) * 8;
    float4 v0 = *(const float4*)(a + base);
    float4 v1 = *(const float4*)(a + base + 4);
    bf16x8 r;
    r[0] = (__bf16)v0.x; r[1] = (__bf16)v0.y; r[2] = (__bf16)v0.z; r[3] = (__bf16)v0.w;
    r[4] = (__bf16)v1.x; r[5] = (__bf16)v1.y; r[6] = (__bf16)v1.z; r[7] = (__bf16)v1.w;
    *(bf16x8*)(o + (size_t)(bid >> 11) * 4194304 + base) = r;
}

// =====================  256x256 2-phase QKV GEMM  ============================
// Tile 256x256, BK=64, 8 waves (2Mx4N), LDS 128KiB dbuf, XOR-swizzle.
// LDS layout is globally linear in row (off(R) = R*64 elems), staged via the
// interleaved 8-row-group units: U0=A rows{0-63,128-191}, U1=A{64-127,192-255},
// U2/U3 = same for B.  Each wave reads: a_lo = rows wm*128+0..63 (in U0),
// a_hi = rows wm*128+64..127 (in U1), b = its B-half cols (spans U2+U3).
//
// Phases (2 per K-tile, 4 barriers, 32-MFMA clusters):
//  phA: read a_lo ks0+1 (8 b128) + b all ni ks0+1 (8); stage U1,U3(kt+1)->Q;
//       WA; BAR; 32 MFMA (m0-3 x n0-3 x ks0-1); BAR.
//  phB: read a_hi (8); stage U0,U2(kt+2)->P; WB; BAR; 32 MFMA (m4-7); BAR.
//
// WAR audit: U1,U3(kt+1)->Q at phA(kt): U1(kt-1)@Q consumed phB(kt-1) cluster,
//  U3(kt-1)@Q consumed phA(kt-1) -> both before phA(kt) opens.  U0,U2(kt+2)->P
//  at phB(kt): consumed at phA(kt).  phB U1-reads vs U0/U2-stage: disjoint addrs.
//
// Wait derivation (4 loads phA + 4 phB per K-tile; prologue 12):
//  Reads at phA(kt) [U0,U2,U3(kt)] protected by WB(kt-1) covering U3(kt)
//    [staged phA(kt-1), newest]: after = phB(kt-1) 4 -> vmcnt(4).
//  Reads at phB(kt) [U1(kt)] protected by WA(kt) covering U1(kt)
//    [staged phA(kt-1)]: after = phB(kt-1) 4 + phA(kt) 4 -> vmcnt(8).
//  Pre-loop: prologue = U0,U2(0)[1-4], U1,U3(0)[5-8], U0,U2(1)[9-12];
//    phA(0) reads need loads 1-8 -> vmcnt(4) + BAR before loop.
//  Tails: kt30: WA=8; phB(30) no stage, WB covers U3(31) [staged phA(30),
//    newest, nothing after] -> vmcnt(0).  kt31: no stages, WA/WB = none.

__device__ __forceinline__ void loadA2(bf16x8 (&a)[4][2], const __bf16* Sp,
                                       int base, int o0, int o1) {
#pragma unroll
    for (int mi = 0; mi < 4; mi++) {
        a[mi][0] = *(const bf16x8*)(Sp + base + mi * 1024 + o0);
        a[mi][1] = *(const bf16x8*)(Sp + base + mi * 1024 + o1);
    }
}
__device__ __forceinline__ void loadB2(bf16x8 (&b)[4][2], const __bf16* Sp,
                                       int base, int o0, int o1) {
#pragma unroll
    for (int j = 0; j < 4; j++) {
        int ro = (j * 16 + (j >> 1) * 32) * 64;
        b[j][0] = *(const bf16x8*)(Sp + base + ro + o0);
        b[j][1] = *(const bf16x8*)(Sp + base + ro + o1);
    }
}

template<int RB>
__device__ __forceinline__ void cluster32(f32x4 (&acc)[8][4], bf16x8 (&a)[4][2],
                                          bf16x8 (&b)[4][2]) {
    __builtin_amdgcn_s_setprio(1);
#pragma unroll
    for (int mi = 0; mi < 4; mi++)
#pragma unroll
        for (int ni = 0; ni < 4; ni++) {
            acc[RB + mi][ni] = __builtin_amdgcn_mfma_f32_16x16x32_bf16(
                a[mi][0], b[ni][0], acc[RB + mi][ni], 0, 0, 0);
            acc[RB + mi][ni] = __builtin_amdgcn_mfma_f32_16x16x32_bf16(
                a[mi][1], b[ni][1], acc[RB + mi][ni], 0, 0, 0);
        }
    __builtin_amdgcn_s_setprio(0);
}

#define FENCE asm volatile("" ::: "memory")
#define BAR   do { FENCE; __builtin_amdgcn_s_barrier(); FENCE; } while (0)
#define VM8   asm volatile("s_waitcnt vmcnt(8)" ::: "memory")
#define VM4   asm volatile("s_waitcnt vmcnt(4)" ::: "memory")
#define VM0   asm volatile("s_waitcnt vmcnt(0)" ::: "memory")
#define VMX   do {} while (0)

// stage A/B half HF (0: rows {0-63,128-191}; 1: rows {64-127,192-255}) of
// K-tile kt into buf P.  Per-wave: rowgroups {HF*8+w, HF*8+16+w}.
#define STGA(P, kt, HF) do { \
    gload_lds16(pA + (size_t)((HF) * 64 + w * 8) * DM + (kt) * 64,       &As[P][((HF) * 8 + w) * 512]); \
    gload_lds16(pA + (size_t)((HF) * 64 + 128 + w * 8) * DM + (kt) * 64, &As[P][((HF) * 8 + 16 + w) * 512]); \
} while (0)
#define STGB(P, kt, HF) do { \
    gload_lds16(pB + (size_t)((HF) * 64 + w * 8) * DM + (kt) * 64,       &Bs[P][((HF) * 8 + w) * 512]); \
    gload_lds16(pB + (size_t)((HF) * 64 + 128 + w * 8) * DM + (kt) * 64, &Bs[P][((HF) * 8 + 16 + w) * 512]); \
} while (0)

#define KT2(kt, P, Q, SGA, SGB, WA, WB) do { \
    /* phA: m0-3 x all n x ks0-1 */ \
    loadA2(a, &As[P][0], baseA, o0, o1); \
    loadB2(b, &Bs[P][0], baseB, o0, o1); \
    if (SGA) { STGA(Q, (kt) + 1, 1); STGB(Q, (kt) + 1, 1); } \
    WA; BAR; cluster32<0>(acc, a, b); BAR; \
    /* phB: m4-7 x all n x ks0-1 (b reused) */ \
    loadA2(a, &As[P][0], baseA + 4096, o0, o1); \
    if (SGB) { STGA(P, (kt) + 2, 0); STGB(P, (kt) + 2, 0); } \
    WB; BAR; cluster32<4>(acc, a, b); BAR; \
} while (0)

__global__ __launch_bounds__(512, 2)
void gemm_qkv(const __bf16* __restrict__ A,
              const __bf16* __restrict__ Wq,
              const __bf16* __restrict__ Wk,
              const __bf16* __restrict__ Wv,
              float* __restrict__ out) {
    __shared__ __bf16 As[2][16384];   // 2 x 256x64
    __shared__ __bf16 Bs[2][16384];

    int tid = threadIdx.x;
    int w = tid >> 6, l = tid & 63;
    int wm = w >> 2, wn = w & 3;

    // 2D-clustered XCD mapping (R6, verified): xcd owns 8mt x 12nt region;
    // each round's 32 co-resident blocks form a 4x8 / 8x4 cluster in L2.
    int bid = blockIdx.x;
    int x = bid & 7;
    int ridx = bid >> 3;               // 0..95
    int q = ridx >> 5;                 // round 0,1,2
    int s = ridx & 31;
    int mtp, ntp;
    if (q == 0)      { mtp = s >> 3;       ntp = s & 7; }
    else if (q == 1) { mtp = 4 + (s >> 3); ntp = s & 7; }
    else             { mtp = s & 7;        ntp = 8 + (s >> 3); }
    int mt = (x & 3) * 8 + mtp;        // 0..31
    int nt = (x >> 2) * 12 + ntp;      // 0..23
    int mat = nt >> 3, ntb = nt & 7;
    const __bf16* Wp = (mat == 0) ? Wq : (mat == 1) ? Wk : Wv;
    int row0 = mt * 256, colp = ntb * 256;

    // staging base pointers: lane covers row lr of each 8-row group, 16B at
    // pre-swizzled col ((l&7)^(l>>3))*16B  (rule 21: swizzle source, linear dest)
    int lr = l >> 3;
    int lco = ((l & 7) ^ lr) * 8;
    const __bf16* pA = A  + (size_t)(row0 + lr) * DM + lco;
    const __bf16* pB = Wp + (size_t)(colp + lr) * DM + lco;

    // ds_read lane constants (elements); read-side XOR matches write swizzle
    int baseA = (wm * 128 + (l & 15)) * 64;
    int baseB = ((wn & 1) * 32 + (wn >> 1) * 128 + (l & 15)) * 64;
    int o0 = ((l >> 4) * 8) ^ ((l & 7) * 8);
    int o1 = o0 ^ 32;

    // prologue: U0,U2(0) [loads 1-4], U1,U3(0) [5-8], U0,U2(1) [9-12]
    STGA(0, 0, 0); STGB(0, 0, 0);
    STGA(0, 0, 1); STGB(0, 0, 1);
    STGA(1, 1, 0); STGB(1, 1, 0);

    f32x4 acc[8][4];
#pragma unroll
    for (int i = 0; i < 8; i++)
#pragma unroll
        for (int j = 0; j < 4; j++)
            acc[i][j] = (f32x4){0.f, 0.f, 0.f, 0.f};

    bf16x8 a[4][2], b[4][2];

    VM4;          // loads 1-8 = U0,U2,U3,U1(kt0) landed before first ds_read
    BAR;

#pragma unroll 1
    for (int kt = 0; kt < 30; kt += 2) {
        KT2(kt,     0, 1, 1, 1, VM8, VM4);
        KT2(kt + 1, 1, 0, 1, 1, VM8, VM4);
    }
    KT2(30, 0, 1, 1, 0, VM8, VM0);   // stages only U1,U3(31)
    KT2(31, 1, 0, 0, 0, VMX, VMX);

    // ---------------- epilogue: head-split layout + fused RoPE ---------------
    // acc[mi][ni] col = (wn&1)*32 + (ni&1)*16 + (wn>>1)*128 + (ni>>1)*64 + (l&15)
    // -> (acc[mi][ni], acc[mi][ni+2]) is the (d, d+64) rotation pair, ni=0,1.
    float* op = out + (size_t)mat * MAT_ELEMS;
    int hd_lo = (wn & 1) * 32 + (l & 15);                 // d for ni=0 (0..63)
    int head = ntb * 2 + (wn >> 1);
    int r_base = row0 + wm * 128 + ((l >> 4) << 2);
    float if0 = exp2f(-0.20762051f * (float)hd_lo);        // 10000^(-d/64)
    float if1 = exp2f(-0.20762051f * (float)(hd_lo + 16));

    if (mat < 2) {
#pragma unroll
        for (int mi = 0; mi < 8; mi++) {
#pragma unroll
            for (int j = 0; j < 4; j++) {
                int r = r_base + mi * 16 + j;
                int b2 = r >> 12, n = r & 4095;
                float fn = (float)n;
                float* rowp = op + ((size_t)((b2 * NH + head) * NSEQ + n)) * HD;
#pragma unroll
                for (int ni = 0; ni < 2; ni++) {
                    float lo = acc[mi][ni][j], hi = acc[mi][ni + 2][j];
                    float sv, cv;
                    __sincosf(fn * (ni ? if1 : if0), &sv, &cv);
                    rowp[hd_lo + ni * 16]      = lo * cv - hi * sv;
                    rowp[hd_lo + ni * 16 + 64] = hi * cv + lo * sv;
                }
            }
        }
    } else {
#pragma unroll
        for (int mi = 0; mi < 8; mi++) {
#pragma unroll
            for (int j = 0; j < 4; j++) {
                int r = r_base + mi * 16 + j;
                int b2 = r >> 12, n = r & 4095;
                float* rowp = op + ((size_t)((b2 * NH + head) * NSEQ + n)) * HD;
#pragma unroll
                for (int ni = 0; ni < 2; ni++) {
                    rowp[hd_lo + ni * 16]      = acc[mi][ni][j];
                    rowp[hd_lo + ni * 16 + 64] = acc[mi][ni + 2][j];
                }
            }
        }
    }
}

// ---------------------------------------------------------------------------
extern "C" void kernel_launch(void* const* d_in, const int* in_sizes, int n_in,
                              void* d_out, int out_size, void* d_ws, size_t ws_size,
                              hipStream_t stream) {
    const float* x  = (const float*)d_in[0];
    const float* g  = (const float*)d_in[1];
    const float* be = (const float*)d_in[2];
    const float* wq = (const float*)d_in[3];
    const float* wk = (const float*)d_in[4];
    const float* wv = (const float*)d_in[5];
    float* out = (float*)d_out;

    char* ws = (char*)d_ws;
    __bf16* xnb = (__bf16*)ws;                                   // 32 MB
    __bf16* wb  = (__bf16*)(ws + 33554432);                      // 24 MB (q,k,v)

    ln_kernel<<<NROWS, 256, 0, stream>>>(x, g, be, xnb);
    cvt3_kernel<<<6144, 256, 0, stream>>>(wq, wk, wv, wb);
    gemm_qkv<<<768, 512, 0, stream>>>(xnb, wb, wb + 4194304, wb + 8388608, out);
}

// Round 12
// 221.540 us; speedup vs baseline: 1.0553x; 1.0440x over previous
//
#include <hip/hip_runtime.h>
#include <hip/hip_bf16.h>

// Fused LN -> QKV projection (bf16 MFMA, 256^2, 4-phase schedule with
// m201-style single counted vmcnt per K-tile, 2D-clustered XCD mapping),
// RoPE fused into the GEMM epilogue.
// x:(2,4096,2048) f32; wq/wk/wv:(2048,2048) f32 row-major [e][d]; out: q,k,v
// each (2,16,4096,128) f32 concatenated.

typedef float f32x4 __attribute__((ext_vector_type(4)));
typedef __bf16 bf16x8 __attribute__((ext_vector_type(8)));
typedef __bf16 bf16x4 __attribute__((ext_vector_type(4)));

#define DM    2048
#define NSEQ  4096
#define NH    16
#define HD    128
#define NROWS 8192
#define MAT_ELEMS (2ull*NH*NSEQ*HD)

// ---------- async global->LDS (16B/lane, wave-uniform LDS base) --------------
typedef __attribute__((address_space(1))) const void GV;
typedef __attribute__((address_space(3))) void LV;
__device__ __forceinline__ void gload_lds16(const void* g, void* l) {
    __builtin_amdgcn_global_load_lds((GV*)g, (LV*)l, 16, 0, 0);
}

// ------------- LayerNorm + weight f32->bf16 cast, single launch --------------
__global__ __launch_bounds__(256)
void lncvt_kernel(const float* __restrict__ x, const float* __restrict__ g,
                  const float* __restrict__ be,
                  const float* __restrict__ wq, const float* __restrict__ wk,
                  const float* __restrict__ wv,
                  __bf16* __restrict__ xnb, __bf16* __restrict__ wb) {
    int bid = blockIdx.x;
    int tid = threadIdx.x;
    if (bid < NROWS) {
        // ---- LayerNorm of row bid ----
        int row = bid;
        const float4* xr = (const float4*)(x + (size_t)row * DM);
        float4 v0 = xr[tid];
        float4 v1 = xr[tid + 256];
        float s  = v0.x + v0.y + v0.z + v0.w + v1.x + v1.y + v1.z + v1.w;
        float ss = v0.x*v0.x + v0.y*v0.y + v0.z*v0.z + v0.w*v0.w
                 + v1.x*v1.x + v1.y*v1.y + v1.z*v1.z + v1.w*v1.w;
#pragma unroll
        for (int o = 32; o > 0; o >>= 1) {
            s  += __shfl_down(s, o);
            ss += __shfl_down(ss, o);
        }
        __shared__ float red[10];
        int wave = tid >> 6, lane = tid & 63;
        if (lane == 0) { red[wave] = s; red[4 + wave] = ss; }
        __syncthreads();
        if (tid == 0) {
            float S  = red[0] + red[1] + red[2] + red[3];
            float SS = red[4] + red[5] + red[6] + red[7];
            float mu  = S * (1.0f / DM);
            float var = SS * (1.0f / DM) - mu * mu;
            red[8] = mu;
            red[9] = rsqrtf(var + 1e-5f);
        }
        __syncthreads();
        float mu = red[8], rs = red[9];

        const float4* gp = (const float4*)g;
        const float4* bp = (const float4*)be;
        bf16x4* orow = (bf16x4*)(xnb + (size_t)row * DM);
        {
            float4 g0 = gp[tid], b0 = bp[tid];
            bf16x4 o;
            o[0] = (__bf16)((v0.x - mu) * rs * g0.x + b0.x);
            o[1] = (__bf16)((v0.y - mu) * rs * g0.y + b0.y);
            o[2] = (__bf16)((v0.z - mu) * rs * g0.z + b0.z);
            o[3] = (__bf16)((v0.w - mu) * rs * g0.w + b0.w);
            orow[tid] = o;
        }
        {
            float4 g1 = gp[tid + 256], b1 = bp[tid + 256];
            bf16x4 o;
            o[0] = (__bf16)((v1.x - mu) * rs * g1.x + b1.x);
            o[1] = (__bf16)((v1.y - mu) * rs * g1.y + b1.y);
            o[2] = (__bf16)((v1.z - mu) * rs * g1.z + b1.z);
            o[3] = (__bf16)((v1.w - mu) * rs * g1.w + b1.w);
            orow[tid + 256] = o;
        }
    } else {
        // ---- weight conversion ----
        int cb = bid - NROWS;                   // 0..6143
        const float* a = (cb < 2048) ? wq : (cb < 4096) ? wk : wv;
        size_t base = ((size_t)(cb & 2047) * 256 + tid) * 8;
        float4 v0 = *(const float4*)(a + base);
        float4 v1 = *(const float4*)(a + base + 4);
        bf16x8 r;
        r[0] = (__bf16)v0.x; r[1] = (__bf16)v0.y; r[2] = (__bf16)v0.z; r[3] = (__bf16)v0.w;
        r[4] = (__bf16)v1.x; r[5] = (__bf16)v1.y; r[6] = (__bf16)v1.z; r[7] = (__bf16)v1.w;
        *(bf16x8*)(wb + (size_t)(cb >> 11) * 4194304 + base) = r;
    }
}

// =====================  256x256 4-phase QKV GEMM  ============================
// Tile 256x256, BK=64, 8 waves (2Mx4N), LDS 128KiB dbuf, XOR-swizzle.
// Units: U0=A rows{0-63,128-191}, U1=A rows{64-127,192-255}; U2/U3 = B same.
// Reads: ph0 = U0(A m0-3) + U2(B cb0); ph1 = U3(B cb2); ph2 = U1(A m4-7);
// ph3 = none (registers only).
// Stages: ph0 -> U1(kt+1)->Q; ph1 -> U0(kt+2)->P; ph2 -> U2(kt+2)->P;
// ph3 -> U3(kt+2)->P.  (R6 placement, WAR-proven.)
//
// m201-style waits: ONE vmcnt per K-tile, at ph3 after its stage:
//   steady: covers U1(kt+1) [staged ph0(kt)]; loads after = ph1+ph2+ph3 = 6
//     -> vmcnt(6).  All older units (U0/U2/U3(kt+1), staged kt-1) implied.
//   pre-loop: 14 prologue loads, kt0 needs loads 1-8 (U0,U2,U3,U1(0))
//     -> vmcnt(6) + BAR.
//   tails: kt30 stages only U1(31) at ph0 -> W3 = vmcnt(0); kt31 no stage,
//     no wait (covered by kt30's drain).
// Each opening barrier is followed by explicit lgkmcnt(0) + sched_barrier(0)
// (template's deterministic ds_read->MFMA gate).

__device__ __forceinline__ void loadA4(bf16x8 (&a)[4][2], const __bf16* Sp,
                                       int base, int mb, int o0) {
#pragma unroll
    for (int mi = 0; mi < 4; mi++)
#pragma unroll
        for (int ks = 0; ks < 2; ks++)
            a[mi][ks] = *(const bf16x8*)(Sp + base + (mb + mi) * 1024 + (o0 ^ (ks * 32)));
}
// fragments f=0,1 at B rows base + f*16 + (cb>>1)*64
__device__ __forceinline__ void loadB2(bf16x8 (&b)[2][2], const __bf16* Sp,
                                       int base, int cb, int o0) {
#pragma unroll
    for (int f = 0; f < 2; f++)
#pragma unroll
        for (int ks = 0; ks < 2; ks++)
            b[f][ks] = *(const bf16x8*)(Sp + base + (f * 16 + (cb >> 1) * 64) * 64 + (o0 ^ (ks * 32)));
}

template<int RB, int CB>
__device__ __forceinline__ void cluster(f32x4 (&acc)[8][4], bf16x8 (&a)[4][2],
                                        bf16x8 (&b)[2][2]) {
    __builtin_amdgcn_s_setprio(1);
#pragma unroll
    for (int mi = 0; mi < 4; mi++)
#pragma unroll
        for (int ni = 0; ni < 2; ni++)
#pragma unroll
            for (int ks = 0; ks < 2; ks++)
                acc[RB + mi][CB + ni] = __builtin_amdgcn_mfma_f32_16x16x32_bf16(
                    a[mi][ks], b[ni][ks], acc[RB + mi][CB + ni], 0, 0, 0);
    __builtin_amdgcn_s_setprio(0);
}

#define FENCE asm volatile("" ::: "memory")
#define BAR   do { FENCE; __builtin_amdgcn_s_barrier(); FENCE; } while (0)
// opening barrier: sync, then hard lgkm gate before MFMA (template pattern)
#define BARO  do { BAR; asm volatile("s_waitcnt lgkmcnt(0)" ::: "memory"); \
                   __builtin_amdgcn_sched_barrier(0); } while (0)
#define VM6   asm volatile("s_waitcnt vmcnt(6)" ::: "memory")
#define VM0   asm volatile("s_waitcnt vmcnt(0)" ::: "memory")
#define VMX   do {} while (0)

// stage A/B half HF (0: rows {0-63,128-191}; 1: rows {64-127,192-255}) of
// K-tile kt into buf P.  Per-wave: rowgroups {HF*8+w, HF*8+16+w}.
#define STGA(P, kt, HF) do { \
    gload_lds16(pA + (size_t)((HF) * 64 + w * 8) * DM + (kt) * 64,       &As[P][((HF) * 8 + w) * 512]); \
    gload_lds16(pA + (size_t)((HF) * 64 + 128 + w * 8) * DM + (kt) * 64, &As[P][((HF) * 8 + 16 + w) * 512]); \
} while (0)
#define STGB(P, kt, HF) do { \
    gload_lds16(pB + (size_t)((HF) * 64 + w * 8) * DM + (kt) * 64,       &Bs[P][((HF) * 8 + w) * 512]); \
    gload_lds16(pB + (size_t)((HF) * 64 + 128 + w * 8) * DM + (kt) * 64, &Bs[P][((HF) * 8 + 16 + w) * 512]); \
} while (0)

#define KTILE(kt, P, Q, SG0, SG1, SG2, SG3, W3) do { \
    /* ph0: quad (0,0) */ \
    loadA4(a,  &As[P][0], baseA, 0, o0); \
    loadB2(b0, &Bs[P][0], baseB, 0, o0); \
    if (SG0) STGA(Q, (kt) + 1, 1);               /* U1(kt+1) */ \
    BARO; cluster<0, 0>(acc, a, b0); BAR; \
    /* ph1: quad (0,2) */ \
    loadB2(b1, &Bs[P][0], baseB, 2, o0); \
    if (SG1) STGA(P, (kt) + 2, 0);               /* U0(kt+2) */ \
    BARO; cluster<0, 2>(acc, a, b1); BAR; \
    /* ph2: quad (4,2) */ \
    loadA4(a, &As[P][0], baseA, 4, o0); \
    if (SG2) STGB(P, (kt) + 2, 0);               /* U2(kt+2) */ \
    BARO; cluster<4, 2>(acc, a, b1); BAR; \
    /* ph3: quad (4,0) */ \
    if (SG3) STGB(P, (kt) + 2, 1);               /* U3(kt+2) */ \
    W3; \
    BARO; cluster<4, 0>(acc, a, b0); BAR; \
} while (0)

__global__ __launch_bounds__(512, 2)
void gemm_qkv(const __bf16* __restrict__ A,
              const __bf16* __restrict__ Wq,
              const __bf16* __restrict__ Wk,
              const __bf16* __restrict__ Wv,
              float* __restrict__ out) {
    __shared__ __bf16 As[2][16384];   // 2 x 256x64
    __shared__ __bf16 Bs[2][16384];

    int tid = threadIdx.x;
    int w = tid >> 6, l = tid & 63;
    int wm = w >> 2, wn = w & 3;

    // 2D-clustered XCD mapping (R6, verified): xcd owns 8mt x 12nt region;
    // each round's 32 co-resident blocks form a 4x8 / 8x4 cluster in L2.
    int bid = blockIdx.x;
    int x = bid & 7;
    int ridx = bid >> 3;               // 0..95
    int q = ridx >> 5;                 // round 0,1,2
    int s = ridx & 31;
    int mtp, ntp;
    if (q == 0)      { mtp = s >> 3;       ntp = s & 7; }
    else if (q == 1) { mtp = 4 + (s >> 3); ntp = s & 7; }
    else             { mtp = s & 7;        ntp = 8 + (s >> 3); }
    int mt = (x & 3) * 8 + mtp;        // 0..31
    int nt = (x >> 2) * 12 + ntp;      // 0..23
    int mat = nt >> 3, ntb = nt & 7;
    const __bf16* Wp = (mat == 0) ? Wq : (mat == 1) ? Wk : Wv;
    int row0 = mt * 256, colp = ntb * 256;

    // staging base pointers: lane covers row lr of each 8-row group, 16B at
    // pre-swizzled col ((l&7)^(l>>3))*16B  (rule 21: swizzle source, linear dest)
    int lr = l >> 3;
    int lco = ((l & 7) ^ lr) * 8;
    const __bf16* pA = A  + (size_t)(row0 + lr) * DM + lco;
    const __bf16* pB = Wp + (size_t)(colp + lr) * DM + lco;

    // ds_read lane constants (elements); read-side XOR matches write swizzle
    int baseA = (wm * 128 + (l & 15)) * 64;
    int baseB = ((wn & 1) * 32 + (wn >> 1) * 128 + (l & 15)) * 64;
    int o0 = ((l >> 4) * 8) ^ ((l & 7) * 8);

    // prologue: U0,U1,U2,U3(kt0)->buf0 [loads 1-8]; U0,U2,U3(kt1)->buf1 [9-14]
    STGA(0, 0, 0); STGB(0, 0, 0); STGB(0, 0, 1); STGA(0, 0, 1);
    STGA(1, 1, 0); STGB(1, 1, 0); STGB(1, 1, 1);

    f32x4 acc[8][4];
#pragma unroll
    for (int i = 0; i < 8; i++)
#pragma unroll
        for (int j = 0; j < 4; j++)
            acc[i][j] = (f32x4){0.f, 0.f, 0.f, 0.f};

    bf16x8 a[4][2], b0[2][2], b1[2][2];

    VM6;          // loads 1-8 = all of kt0 landed before first ds_read
    BAR;

#pragma unroll 1
    for (int kt = 0; kt < 30; kt += 2) {
        KTILE(kt,     0, 1, 1, 1, 1, 1, VM6);
        KTILE(kt + 1, 1, 0, 1, 1, 1, 1, VM6);
    }
    KTILE(30, 0, 1, 1, 0, 0, 0, VM0);   // stages only U1(31); drain
    KTILE(31, 1, 0, 0, 0, 0, 0, VMX);

    // ---------------- epilogue: head-split layout + fused RoPE ---------------
    // acc[mi][ni] col = (wn&1)*32 + (ni&1)*16 + (wn>>1)*128 + (ni>>1)*64 + (l&15)
    // -> (acc[mi][ni], acc[mi][ni+2]) is the (d, d+64) rotation pair, ni=0,1.
    float* op = out + (size_t)mat * MAT_ELEMS;
    int hd_lo = (wn & 1) * 32 + (l & 15);                 // d for ni=0 (0..63)
    int head = ntb * 2 + (wn >> 1);
    int r_base = row0 + wm * 128 + ((l >> 4) << 2);
    float if0 = exp2f(-0.20762051f * (float)hd_lo);        // 10000^(-d/64)
    float if1 = exp2f(-0.20762051f * (float)(hd_lo + 16));

    if (mat < 2) {
#pragma unroll
        for (int mi = 0; mi < 8; mi++) {
#pragma unroll
            for (int j = 0; j < 4; j++) {
                int r = r_base + mi * 16 + j;
                int b = r >> 12, n = r & 4095;
                float fn = (float)n;
                float* rowp = op + ((size_t)((b * NH + head) * NSEQ + n)) * HD;
#pragma unroll
                for (int ni = 0; ni < 2; ni++) {
                    float lo = acc[mi][ni][j], hi = acc[mi][ni + 2][j];
                    float sv, cv;
                    __sincosf(fn * (ni ? if1 : if0), &sv, &cv);
                    rowp[hd_lo + ni * 16]      = lo * cv - hi * sv;
                    rowp[hd_lo + ni * 16 + 64] = hi * cv + lo * sv;
                }
            }
        }
    } else {
#pragma unroll
        for (int mi = 0; mi < 8; mi++) {
#pragma unroll
            for (int j = 0; j < 4; j++) {
                int r = r_base + mi * 16 + j;
                int b = r >> 12, n = r & 4095;
                float* rowp = op + ((size_t)((b * NH + head) * NSEQ + n)) * HD;
#pragma unroll
                for (int ni = 0; ni < 2; ni++) {
                    rowp[hd_lo + ni * 16]      = acc[mi][ni][j];
                    rowp[hd_lo + ni * 16 + 64] = acc[mi][ni + 2][j];
                }
            }
        }
    }
}

// ---------------------------------------------------------------------------
extern "C" void kernel_launch(void* const* d_in, const int* in_sizes, int n_in,
                              void* d_out, int out_size, void* d_ws, size_t ws_size,
                              hipStream_t stream) {
    const float* x  = (const float*)d_in[0];
    const float* g  = (const float*)d_in[1];
    const float* be = (const float*)d_in[2];
    const float* wq = (const float*)d_in[3];
    const float* wk = (const float*)d_in[4];
    const float* wv = (const float*)d_in[5];
    float* out = (float*)d_out;

    char* ws = (char*)d_ws;
    __bf16* xnb = (__bf16*)ws;                                   // 32 MB
    __bf16* wb  = (__bf16*)(ws + 33554432);                      // 24 MB (q,k,v)

    lncvt_kernel<<<NROWS + 6144, 256, 0, stream>>>(x, g, be, wq, wk, wv, xnb, wb);
    gemm_qkv<<<768, 512, 0, stream>>>(xnb, wb, wb + 4194304, wb + 8388608, out);
}